// Round 11
// baseline (113.473 us; speedup 1.0000x reference)
//
#include <hip/hip_runtime.h>

#define NN    1024
#define INF   21
#define EE    128
#define NB    65   // 2*BINS+1
#define BINSV 32

typedef float f32x4 __attribute__((ext_vector_type(4)));

// Kernel 1 (merged prep): blocks [0, NN) do the two linear projections;
// blocks [NN, NN+NB) build ptab[d][e] = Wp[e][d] + bp[e].
__global__ __launch_bounds__(128) void prep_kernel(
    const float* __restrict__ tf,
    const float* __restrict__ Wa, const float* __restrict__ ba,
    const float* __restrict__ Wb, const float* __restrict__ bb,
    const float* __restrict__ Wp, const float* __restrict__ bp,
    float* __restrict__ a, float* __restrict__ b, float* __restrict__ ptab) {
  const int e = threadIdx.x;  // 0..127
  if (blockIdx.x < NN) {
    const int i = blockIdx.x;
    __shared__ float row[INF];
    if (e < INF) row[e] = tf[i * INF + e];
    __syncthreads();
    float sa = ba[e];
    float sb = bb[e];
#pragma unroll
    for (int k = 0; k < INF; ++k) {
      float r = row[k];
      sa = fmaf(r, Wa[e * INF + k], sa);
      sb = fmaf(r, Wb[e * INF + k], sb);
    }
    a[i * EE + e] = sa;
    b[i * EE + e] = sb;
  } else {
    const int d = blockIdx.x - NN;  // 0..64
    ptab[d * EE + e] = Wp[e * NB + d] + bp[e];
  }
}

// Kernel 2: R10 structure, but HALF the store streams at DOUBLE the length.
// 1024 blocks x 256 threads (4 waves). Block = row i; wave wv owns j in
// [256*wv, 256*wv+256) = a PRIVATE CONTIGUOUS 128 KB span, storing 1 KB/iter
// marching linearly. Device: 4096 linear write streams, 16 waves/CU.
// 2-deep pipeline on the L2-hit loads; nontemporal stores.
__global__ __launch_bounds__(256) void fill_kernel(
    const float* __restrict__ a, const float* __restrict__ b,
    const float* __restrict__ ptab, const int* __restrict__ ri,
    float* __restrict__ out) {
  __shared__ int sri[NN];
  const int tid = threadIdx.x;
  for (int t = tid; t < NN; t += 256) sri[t] = ri[t];
  __syncthreads();

  const int lane = tid & 63;
  const int hi   = lane >> 5;        // j parity within the 1 KB pair
  const int e4   = lane & 31;        // f32x4 index within E
  const int wv   = tid >> 6;         // wave 0..3
  const int i    = blockIdx.x;
  const int jb   = wv << 8;          // wave's j-span base (256 j's = 128 KB)

  const f32x4* __restrict__ b4 = reinterpret_cast<const f32x4*>(b);
  const f32x4* __restrict__ p4 = reinterpret_cast<const f32x4*>(ptab);

  const f32x4 av = reinterpret_cast<const f32x4*>(a + i * EE)[e4];
  const int rii = sri[i];

  // wave's linear store cursor (f32x4 units); iter t stores at +t*64
  f32x4* __restrict__ o4 = reinterpret_cast<f32x4*>(out) +
      ((size_t)i * NN + jb) * 32 + hi * 32 + e4;

  auto dbin = [&](int j) {
    int d = rii - sri[j];
    return min(max(d, -BINSV), BINSV) + BINSV;
  };

  // 2-deep software pipeline over t = 0..127 (j = jb + 2t + hi)
  int jA = jb + hi;
  f32x4 bv0 = b4[jA * 32 + e4];
  f32x4 pv0 = p4[dbin(jA) * 32 + e4];
  int jB = jb + 2 + hi;
  f32x4 bv1 = b4[jB * 32 + e4];
  f32x4 pv1 = p4[dbin(jB) * 32 + e4];

  for (int t = 0; t < 128; t += 2) {
    const int jn0 = jb + ((2 * t + 4) & 255) + hi;   // masked tail prefetch
    const f32x4 nb0 = b4[jn0 * 32 + e4];
    const f32x4 np0 = p4[dbin(jn0) * 32 + e4];
    __builtin_nontemporal_store(av + bv0 + pv0, o4 + (size_t)t * 64);
    const int jn1 = jb + ((2 * t + 6) & 255) + hi;
    const f32x4 nb1 = b4[jn1 * 32 + e4];
    const f32x4 np1 = p4[dbin(jn1) * 32 + e4];
    __builtin_nontemporal_store(av + bv1 + pv1, o4 + (size_t)(t + 1) * 64);
    bv0 = nb0; pv0 = np0;
    bv1 = nb1; pv1 = np1;
  }
}

extern "C" void kernel_launch(void* const* d_in, const int* in_sizes, int n_in,
                              void* d_out, int out_size, void* d_ws, size_t ws_size,
                              hipStream_t stream) {
  const float* tf = (const float*)d_in[0];
  const int*   ri = (const int*)d_in[1];
  const float* Wa = (const float*)d_in[2];
  const float* ba = (const float*)d_in[3];
  const float* Wb = (const float*)d_in[4];
  const float* bb = (const float*)d_in[5];
  const float* Wp = (const float*)d_in[6];
  const float* bp = (const float*)d_in[7];
  float* out = (float*)d_out;

  float* ws   = (float*)d_ws;
  float* a    = ws;                 // N*E floats
  float* b    = ws + NN * EE;       // N*E floats
  float* ptab = ws + 2 * NN * EE;   // 65*E floats

  prep_kernel<<<NN + NB, 128, 0, stream>>>(tf, Wa, ba, Wb, bb, Wp, bp, a, b, ptab);
  fill_kernel<<<NN, 256, 0, stream>>>(a, b, ptab, ri, out);
}

// Round 12
// 107.155 us; speedup vs baseline: 1.0590x; 1.0590x over previous
//
#include <hip/hip_runtime.h>

#define NN    1024
#define INF   21
#define EE    128
#define NB    65   // 2*BINS+1
#define BINSV 32

typedef float f32x4 __attribute__((ext_vector_type(4)));

// Kernel 1 (merged prep): blocks [0, NN) do the two linear projections;
// blocks [NN, NN+NB) build ptab[d][e] = Wp[e][d] + bp[e].
__global__ __launch_bounds__(128) void prep_kernel(
    const float* __restrict__ tf,
    const float* __restrict__ Wa, const float* __restrict__ ba,
    const float* __restrict__ Wb, const float* __restrict__ bb,
    const float* __restrict__ Wp, const float* __restrict__ bp,
    float* __restrict__ a, float* __restrict__ b, float* __restrict__ ptab) {
  const int e = threadIdx.x;  // 0..127
  if (blockIdx.x < NN) {
    const int i = blockIdx.x;
    __shared__ float row[INF];
    if (e < INF) row[e] = tf[i * INF + e];
    __syncthreads();
    float sa = ba[e];
    float sb = bb[e];
#pragma unroll
    for (int k = 0; k < INF; ++k) {
      float r = row[k];
      sa = fmaf(r, Wa[e * INF + k], sa);
      sb = fmaf(r, Wb[e * INF + k], sb);
    }
    a[i * EE + e] = sa;
    b[i * EE + e] = sb;
  } else {
    const int d = blockIdx.x - NN;  // 0..64
    ptab[d * EE + e] = Wp[e * NB + d] + bp[e];
  }
}

// Kernel 2: R10 champion structure (1024 blocks x 512 thr, block = row i,
// 32 waves/CU, wave wv owns the contiguous 64 KB span j in [128wv, 128wv+128),
// 1 KB/iter marching linearly, 2-deep pipeline) -- with PLAIN stores instead
// of nontemporal (single-variable A/B: nt may bypass Infinity-Cache write
// aggregation; the 6.7 TB/s memset ceiling was set with plain stores).
__global__ __launch_bounds__(512) void fill_kernel(
    const float* __restrict__ a, const float* __restrict__ b,
    const float* __restrict__ ptab, const int* __restrict__ ri,
    float* __restrict__ out) {
  __shared__ int sri[NN];
  const int tid = threadIdx.x;
  for (int t = tid; t < NN; t += 512) sri[t] = ri[t];
  __syncthreads();

  const int lane = tid & 63;
  const int hi   = lane >> 5;        // j parity within the 1 KB pair
  const int e4   = lane & 31;        // f32x4 index within E
  const int wv   = tid >> 6;         // wave 0..7
  const int i    = blockIdx.x;
  const int jb   = wv << 7;          // wave's j-span base (128 j's = 64 KB)

  const f32x4* __restrict__ b4 = reinterpret_cast<const f32x4*>(b);
  const f32x4* __restrict__ p4 = reinterpret_cast<const f32x4*>(ptab);

  const f32x4 av = reinterpret_cast<const f32x4*>(a + i * EE)[e4];
  const int rii = sri[i];

  // wave's linear store cursor (f32x4 units); iter t stores at +t*64
  f32x4* __restrict__ o4 = reinterpret_cast<f32x4*>(out) +
      ((size_t)i * NN + jb) * 32 + hi * 32 + e4;

  auto dbin = [&](int j) {
    int d = rii - sri[j];
    return min(max(d, -BINSV), BINSV) + BINSV;
  };

  // 2-deep software pipeline over t = 0..63 (j = jb + 2t + hi)
  int jA = jb + hi;
  f32x4 bv0 = b4[jA * 32 + e4];
  f32x4 pv0 = p4[dbin(jA) * 32 + e4];
  int jB = jb + 2 + hi;
  f32x4 bv1 = b4[jB * 32 + e4];
  f32x4 pv1 = p4[dbin(jB) * 32 + e4];

  for (int t = 0; t < 64; t += 2) {
    const int jn0 = jb + ((2 * t + 4) & 127) + hi;   // masked tail prefetch
    const f32x4 nb0 = b4[jn0 * 32 + e4];
    const f32x4 np0 = p4[dbin(jn0) * 32 + e4];
    o4[(size_t)t * 64] = av + bv0 + pv0;
    const int jn1 = jb + ((2 * t + 6) & 127) + hi;
    const f32x4 nb1 = b4[jn1 * 32 + e4];
    const f32x4 np1 = p4[dbin(jn1) * 32 + e4];
    o4[(size_t)(t + 1) * 64] = av + bv1 + pv1;
    bv0 = nb0; pv0 = np0;
    bv1 = nb1; pv1 = np1;
  }
}

extern "C" void kernel_launch(void* const* d_in, const int* in_sizes, int n_in,
                              void* d_out, int out_size, void* d_ws, size_t ws_size,
                              hipStream_t stream) {
  const float* tf = (const float*)d_in[0];
  const int*   ri = (const int*)d_in[1];
  const float* Wa = (const float*)d_in[2];
  const float* ba = (const float*)d_in[3];
  const float* Wb = (const float*)d_in[4];
  const float* bb = (const float*)d_in[5];
  const float* Wp = (const float*)d_in[6];
  const float* bp = (const float*)d_in[7];
  float* out = (float*)d_out;

  float* ws   = (float*)d_ws;
  float* a    = ws;                 // N*E floats
  float* b    = ws + NN * EE;       // N*E floats
  float* ptab = ws + 2 * NN * EE;   // 65*E floats

  prep_kernel<<<NN + NB, 128, 0, stream>>>(tf, Wa, ba, Wb, bb, Wp, bp, a, b, ptab);
  fill_kernel<<<NN, 512, 0, stream>>>(a, b, ptab, ri, out);
}